// Round 7
// baseline (216.731 us; speedup 1.0000x reference)
//
#include <hip/hip_runtime.h>
#include <stdint.h>

namespace {

constexpr int kB = 256;
constexpr int kV = 128000;
constexpr int kBlk = 256;
constexpr int kSubs = 5;                  // blocks per row
constexpr int kSpan = kV / kSubs;         // 25600 floats per block
constexpr int kTile = kBlk * 4;           // 1024 floats staged per step (4 KB)
constexpr int kTiles = kSpan / kTile;     // 25

struct Part { float val; int idx; };

// JAX threefry2x32, key = (0, 42). Partitionable mode: bits[i] = o0 ^ o1 of
// threefry(x0=hi32(i)=0, x1=i). Bit-exact vs reference (absmax = 0, R1-R6).
__device__ __forceinline__ uint32_t threefry_bits(uint32_t x1) {
  constexpr uint32_t ks0 = 0u;
  constexpr uint32_t ks1 = 42u;
  constexpr uint32_t ks2 = 0x1BD11BDAu ^ ks0 ^ ks1;
  uint32_t x0 = ks0;
  x1 += ks1;
#define TF_ROUND(r) { x0 += x1; x1 = __builtin_rotateleft32(x1, r); x1 ^= x0; }
  TF_ROUND(13) TF_ROUND(15) TF_ROUND(26) TF_ROUND(6)
  x0 += ks1; x1 += ks2 + 1u;
  TF_ROUND(17) TF_ROUND(29) TF_ROUND(16) TF_ROUND(24)
  x0 += ks2; x1 += ks0 + 2u;
  TF_ROUND(13) TF_ROUND(15) TF_ROUND(26) TF_ROUND(6)
  x0 += ks0; x1 += ks1 + 3u;
  TF_ROUND(17) TF_ROUND(29) TF_ROUND(16) TF_ROUND(24)
  x0 += ks1; x1 += ks2 + 4u;
  TF_ROUND(13) TF_ROUND(15) TF_ROUND(26) TF_ROUND(6)
  x0 += ks2; x1 += ks0 + 5u;
#undef TF_ROUND
  return x0 ^ x1;
}

// gumbel = -ln(-ln(f + tiny)), f = bitcast(bits>>9 | 0x3f800000) - 1.
// Native v_log_f32 * -ln2; bit-stable vs reference across R2-R6 (absmax 0).
__device__ __forceinline__ float gumbel_from_bits(uint32_t bits) {
  constexpr float kTiny = 1.17549435e-38f;  // FLT_MIN
  constexpr float kNegLn2 = -0.69314718055994530942f;
  float f = __uint_as_float((bits >> 9) | 0x3F800000u) - 1.0f;
  float u = f + kTiny;
  float y = __builtin_amdgcn_logf(u) * kNegLn2;   // -ln(u)
  return __builtin_amdgcn_logf(y) * kNegLn2;      // -ln(-ln(u))
}

typedef const __attribute__((address_space(1))) void* gas_ptr;
typedef __attribute__((address_space(3))) void* las_ptr;

__global__ __launch_bounds__(kBlk) void sampler_partial(
    const float* __restrict__ logits, const float* __restrict__ temps,
    Part* __restrict__ parts) {
  const int r = blockIdx.x / kSubs;
  const int s = blockIdx.x % kSubs;
  const int tid = (int)threadIdx.x;
  const float t = temps[r];
  const float* __restrict__ seg = logits + (size_t)r * kV + (size_t)s * kSpan;

  // Async global->LDS double buffer. Each wave stages ONLY its own 1 KB
  // segment (HW places lane l at wave-uniform base + l*16B; our global src
  // advances 16B/lane to match) and reads ONLY that segment back -> no
  // __syncthreads in the loop, just per-wave vmcnt. The intrinsic has no
  // VGPR destination and side effects: the compiler cannot delete or sink
  // this prefetch (R4-R6 post-mortems: every register-based variant died).
  __shared__ alignas(16) float stage_lds[2][kTile];
  const int wavebase = (tid >> 6) << 8;          // wave's 256-float segment
  const float* gsrc = seg + tid * 4;             // +16 B per lane within wave

#define STAGE(b, k)                                                          \
  __builtin_amdgcn_global_load_lds((gas_ptr)(gsrc + (k) * kTile),            \
                                   (las_ptr)(&stage_lds[(b)][wavebase]),     \
                                   16, 0, 0);

  float best = -__builtin_inff();
  int bi = 0;

  STAGE(0, 0)

  if (t == 0.0f) {
    // greedy: argmax of raw logits, first-occurrence tie-break (strict >;
    // per-thread scan order strictly ascending in element index).
#pragma unroll 1
    for (int k = 0; k < kTiles; ++k) {
      if (k + 1 < kTiles) {
        STAGE((k + 1) & 1, k + 1)
        __builtin_amdgcn_s_waitcnt(0x0F71);  // vmcnt(1): tile k resident
      } else {
        __builtin_amdgcn_s_waitcnt(0x0F70);  // vmcnt(0)
      }
      __builtin_amdgcn_sched_barrier(0);
      float4 a = *reinterpret_cast<const float4*>(&stage_lds[k & 1][tid * 4]);
      const int v = s * kSpan + k * kTile + tid * 4;  // index within row
      float la[4] = {a.x, a.y, a.z, a.w};
#pragma unroll
      for (int j = 0; j < 4; ++j) {
        if (la[j] > best) { best = la[j]; bi = v + j; }
      }
    }
  } else {
    // argmax(la/t + g) == argmax(la + t*g) for t > 0 (monotonic, real arith).
#pragma unroll 1
    for (int k = 0; k < kTiles; ++k) {
      if (k + 1 < kTiles) {
        STAGE((k + 1) & 1, k + 1)
        __builtin_amdgcn_s_waitcnt(0x0F71);  // vmcnt(1): tile k resident
      } else {
        __builtin_amdgcn_s_waitcnt(0x0F70);  // vmcnt(0)
      }
      __builtin_amdgcn_sched_barrier(0);
      float4 a = *reinterpret_cast<const float4*>(&stage_lds[k & 1][tid * 4]);
      const int v = s * kSpan + k * kTile + tid * 4;
      const uint32_t base = (uint32_t)(r * kV + v);  // flat index < 2^25
      float la[4] = {a.x, a.y, a.z, a.w};
#pragma unroll
      for (int j = 0; j < 4; ++j) {
        float gb = gumbel_from_bits(threefry_bits(base + (uint32_t)j));
        float key = fmaf(t, gb, la[j]);
        if (key > best) { best = key; bi = v + j; }
      }
    }
  }
#undef STAGE

  __shared__ float sv[kBlk];
  __shared__ int si[kBlk];
  sv[tid] = best;
  si[tid] = bi;
  __syncthreads();
  for (int st = kBlk / 2; st > 0; st >>= 1) {
    if (tid < st) {
      float ov = sv[tid + st]; int oi = si[tid + st];
      float mv = sv[tid];      int mi = si[tid];
      if (ov > mv || (ov == mv && oi < mi)) { sv[tid] = ov; si[tid] = oi; }
    }
    __syncthreads();
  }
  if (tid == 0) {
    parts[r * kSubs + s].val = sv[0];
    parts[r * kSubs + s].idx = si[0];
  }
}

__global__ __launch_bounds__(kB) void sampler_final(
    const Part* __restrict__ parts, int* __restrict__ out) {
  const int r = (int)threadIdx.x;
  if (r < kB) {
    float bv = -__builtin_inff();
    int bi = 0;
#pragma unroll
    for (int g = 0; g < kSubs; ++g) {
      Part p = parts[r * kSubs + g];
      // sub-blocks cover ascending index ranges: strict > + tie -> min idx
      if (p.val > bv || (p.val == bv && p.idx < bi)) { bv = p.val; bi = p.idx; }
    }
    out[r] = bi;
  }
}

}  // namespace

extern "C" void kernel_launch(void* const* d_in, const int* in_sizes, int n_in,
                              void* d_out, int out_size, void* d_ws, size_t ws_size,
                              hipStream_t stream) {
  const float* logits = (const float*)d_in[0];
  const float* temps = (const float*)d_in[1];
  int* out = (int*)d_out;
  Part* parts = (Part*)d_ws;  // kB * kSubs * 8 B = 10 KiB

  sampler_partial<<<dim3(kB * kSubs), dim3(kBlk), 0, stream>>>(logits, temps, parts);
  sampler_final<<<dim3(1), dim3(kB), 0, stream>>>(parts, out);
}